// Round 15
// baseline (359.994 us; speedup 1.0000x reference)
//
#include <hip/hip_runtime.h>
#include <hip/hip_bf16.h>

#define V_ 32000
#define E_ 512
#define H_ 512
#define B_ 32
#define T_ 48
#define NWG 16          // recurrence workgroups (blocks 0..15)
#define NCON 125        // head-consumer workgroups (blocks 17..141)
#define GRID (NWG + 1 + NCON)
#define SPIN_CAP (1 << 20)

typedef __attribute__((ext_vector_type(8))) short bf16x8;
typedef __attribute__((ext_vector_type(4))) float f32x4;
typedef __attribute__((ext_vector_type(4))) int   i32x4;
typedef __attribute__((ext_vector_type(2))) int   i32x2;

static __device__ __forceinline__ short f2bf(float f) {
  union { __hip_bfloat16 h; short s; } u;
  u.h = __float2bfloat16(f);
  return u.s;
}

static __device__ __forceinline__ bf16x8 load_cvt8(const float* p) {
  float4 a = *(const float4*)p;
  float4 b = *(const float4*)(p + 4);
  bf16x8 r;
  r[0] = f2bf(a.x); r[1] = f2bf(a.y); r[2] = f2bf(a.z); r[3] = f2bf(a.w);
  r[4] = f2bf(b.x); r[5] = f2bf(b.y); r[6] = f2bf(b.z); r[7] = f2bf(b.w);
  return r;
}

static __device__ __forceinline__ float sigf(float x) {
  return 1.0f / (1.0f + __expf(-x));
}
static __device__ __forceinline__ float tanh_fast(float x) {
  float e = __expf(2.0f * x);
  return (e - 1.0f) / (e + 1.0f);
}

// device-coherent 4B load, acked
static __device__ __forceinline__ unsigned prog_load(const unsigned* p) {
  unsigned v;
  asm volatile("global_load_dword %0, %1, off sc0 sc1\n\t"
               "s_waitcnt vmcnt(0)"
               : "=&v"(v) : "v"(p) : "memory");
  return v;
}

// 16 coherent dwordx4 loads, contiguous 256B, one trailing ack.
// NOTE: the vmcnt(0) also drains this wave's PRIOR STORES -> implicit free ack.
#define PLOADS16(T, ADDR)                                              \
  asm volatile(                                                        \
    "global_load_dwordx4 %0,  %16, off sc0 sc1\n\t"                    \
    "global_load_dwordx4 %1,  %16, off offset:16 sc0 sc1\n\t"          \
    "global_load_dwordx4 %2,  %16, off offset:32 sc0 sc1\n\t"          \
    "global_load_dwordx4 %3,  %16, off offset:48 sc0 sc1\n\t"          \
    "global_load_dwordx4 %4,  %16, off offset:64 sc0 sc1\n\t"          \
    "global_load_dwordx4 %5,  %16, off offset:80 sc0 sc1\n\t"          \
    "global_load_dwordx4 %6,  %16, off offset:96 sc0 sc1\n\t"          \
    "global_load_dwordx4 %7,  %16, off offset:112 sc0 sc1\n\t"         \
    "global_load_dwordx4 %8,  %16, off offset:128 sc0 sc1\n\t"         \
    "global_load_dwordx4 %9,  %16, off offset:144 sc0 sc1\n\t"         \
    "global_load_dwordx4 %10, %16, off offset:160 sc0 sc1\n\t"         \
    "global_load_dwordx4 %11, %16, off offset:176 sc0 sc1\n\t"         \
    "global_load_dwordx4 %12, %16, off offset:192 sc0 sc1\n\t"         \
    "global_load_dwordx4 %13, %16, off offset:208 sc0 sc1\n\t"         \
    "global_load_dwordx4 %14, %16, off offset:224 sc0 sc1\n\t"         \
    "global_load_dwordx4 %15, %16, off offset:240 sc0 sc1\n\t"         \
    "s_waitcnt vmcnt(0)"                                               \
    : "=&v"(T[0]),  "=&v"(T[1]),  "=&v"(T[2]),  "=&v"(T[3]),           \
      "=&v"(T[4]),  "=&v"(T[5]),  "=&v"(T[6]),  "=&v"(T[7]),           \
      "=&v"(T[8]),  "=&v"(T[9]),  "=&v"(T[10]), "=&v"(T[11]),          \
      "=&v"(T[12]), "=&v"(T[13]), "=&v"(T[14]), "=&v"(T[15])           \
    : "v"(ADDR) : "memory")

// 4 coherent 16B loads, contiguous 64B, acked
#define CLOADS4(T, ADDR)                                               \
  asm volatile(                                                        \
    "global_load_dwordx4 %0, %4, off sc0 sc1\n\t"                      \
    "global_load_dwordx4 %1, %4, off offset:16 sc0 sc1\n\t"            \
    "global_load_dwordx4 %2, %4, off offset:32 sc0 sc1\n\t"            \
    "global_load_dwordx4 %3, %4, off offset:48 sc0 sc1\n\t"            \
    "s_waitcnt vmcnt(0)"                                               \
    : "=&v"(T[0]), "=&v"(T[1]), "=&v"(T[2]), "=&v"(T[3])               \
    : "v"(ADDR) : "memory")

// coherent stores, fire-and-forget
#define DSTORE(ADDR, VAL)                                              \
  asm volatile("global_store_dword %0, %1, off sc0 sc1"                \
               :: "v"(ADDR), "v"(VAL) : "memory")
#define DSTORE2(ADDR, VAL)                                             \
  asm volatile("global_store_dwordx2 %0, %1, off sc0 sc1"              \
               :: "v"(ADDR), "v"(VAL) : "memory")
#define QSTORE(ADDR, VAL)                                              \
  asm volatile("global_store_dwordx4 %0, %1, off sc0 sc1"              \
               :: "v"(ADDR), "v"(VAL) : "memory")

// ---------------------------------------------------------------------------
// Kernel 1: Xg[t][b][j] = x_t[b] @ W_ih^T [j] + b_ih[j] + b_hh[j]
// ---------------------------------------------------------------------------
__global__ __launch_bounds__(256) void k_xg(
    const float* __restrict__ img,   // [32][512]
    const int*   __restrict__ gt,    // [32][48]
    const float* __restrict__ emb,   // [32000][512]
    const float* __restrict__ W_ih,  // [2048][512]
    const float* __restrict__ b_ih,
    const float* __restrict__ b_hh,
    float* __restrict__ Xg)          // [48][32][2048]
{
  const int s    = blockIdx.x;
  const int lane = threadIdx.x & 63;
  const int wv   = threadIdx.x >> 6;
  const int nbase = blockIdx.y * 256 + wv * 64;
  const int lr  = lane & 15;
  const int lkb = lane >> 4;

  const float* arow[2];
#pragma unroll
  for (int m = 0; m < 2; ++m) {
    int b = m * 16 + lr;
    const float* src;
    if (s == 0) {
      src = img + b * E_;
    } else {
      int tok = (s == 1) ? 1 : gt[b * T_ + (s - 1)];
      src = emb + (long)tok * E_;
    }
    arow[m] = src;
  }

  f32x4 acc[2][4];
#pragma unroll
  for (int m = 0; m < 2; ++m)
#pragma unroll
    for (int n = 0; n < 4; ++n) acc[m][n] = (f32x4){0.f, 0.f, 0.f, 0.f};

  for (int kt = 0; kt < 16; ++kt) {
    int ko = kt * 32 + lkb * 8;
    bf16x8 a0 = load_cvt8(arow[0] + ko);
    bf16x8 a1 = load_cvt8(arow[1] + ko);
#pragma unroll
    for (int n = 0; n < 4; ++n) {
      const float* wp = W_ih + (long)(nbase + n * 16 + lr) * E_ + ko;
      bf16x8 bw = load_cvt8(wp);
      acc[0][n] = __builtin_amdgcn_mfma_f32_16x16x32_bf16(a0, bw, acc[0][n], 0, 0, 0);
      acc[1][n] = __builtin_amdgcn_mfma_f32_16x16x32_bf16(a1, bw, acc[1][n], 0, 0, 0);
    }
  }

#pragma unroll
  for (int n = 0; n < 4; ++n) {
    int j = nbase + n * 16 + lr;
    float bias = b_ih[j] + b_hh[j];
#pragma unroll
    for (int m = 0; m < 2; ++m) {
#pragma unroll
      for (int r = 0; r < 4; ++r) {
        int b = m * 16 + lkb * 4 + r;
        Xg[((long)(s * B_ + b) * 2048) + j] = acc[m][n][r] + bias;
      }
    }
  }
}

// ---------------------------------------------------------------------------
// Kernel 2 (fused):
//  blocks 0..15 : recurrence (R14 geometry). h exchange = tagged {2xbf16,tag}
//                 8B units in hxc[2 parity][32 b][256 u]; store at step t
//                 carries tag t+1 into parity (t+1)&1 -> polled at step t+1.
//                 ONE visibility hop on the critical path; the poll's
//                 vmcnt(0) drains the previous step's stores for free.
//                 Flags are LAZY consumer-epochs (fired post-poll, value t:
//                 guarantees hs rows of steps <= t-1 are drained).
//  block 16     : aggregator: 16 flags -> 64 epoch replica lines.
//  blocks 17..141: head consumers (256 v-rows); poll ONE replica line
//                 (>= mt/2+2), then bulk plain hs read. R14 verbatim.
// Grid 142 x 144KB LDS -> 1 block/CU -> all co-resident. Spins bounded.
// ---------------------------------------------------------------------------
__global__ __launch_bounds__(256, 1) void k_fused(
    const float* __restrict__ W_hh,      // [2048][512]
    const float* __restrict__ Xg,        // [48][32][2048]
    const float* __restrict__ W_head,    // [32000][512]
    const float* __restrict__ b_head,    // [32000]
    unsigned* __restrict__ flags,        // [16] lines (128B apart)
    unsigned* __restrict__ replicas,     // [64] lines (128B apart)
    char* __restrict__ hxc,              // [2][32][256u] x 8B tagged
    unsigned short* __restrict__ hs,     // [1504][512] bf16 plain
    float* __restrict__ out)             // [48][32][32000]
{
  __shared__ __align__(16) char lds[147456];  // prod: 96K W + 32K stage + 16K gbuf
  const int tid  = threadIdx.x;
  const int lane = tid & 63;
  const int wv   = tid >> 6;
  const int lr   = lane & 15;
  const int lkb  = lane >> 4;

  if (blockIdx.x < NWG) {
    // ===================== recurrence role =====================
    char* wlds  = lds;             // [4 wv][2 rt][12 kt][64 lane][16B] = 96KB
    char* stage = lds + 98304;     // pure h [32 b][512] bf16 swizzled = 32KB
    char* gbufc = lds + 131072;    // [4 gate][32 b][32 d] f32 = 16KB
    const int w = blockIdx.x;      // owns hidden dims [32w, 32w+32)
    const int g = wv;              // wave = gate

    // W_hh fragments: kt 0..11 -> LDS, kt 12..15 -> registers
    bf16x8 awr[2][4];
#pragma unroll
    for (int rt = 0; rt < 2; ++rt) {
      int row = g * 512 + w * 32 + rt * 16 + lr;
#pragma unroll
      for (int kt = 0; kt < 12; ++kt) {
        bf16x8 wf = load_cvt8(W_hh + (long)row * E_ + kt * 32 + lkb * 8);
        *(bf16x8*)(wlds + ((((wv * 2 + rt) * 12 + kt) * 64) + lane) * 16) = wf;
      }
#pragma unroll
      for (int kt = 12; kt < 16; ++kt)
        awr[rt][kt - 12] = load_cvt8(W_hh + (long)row * E_ + kt * 32 + lkb * 8);
    }

    // cell ownership: thread j -> b = j>>3, local dims di..di+3 (di=(j&7)*4)
    const int cb_b  = tid >> 3;
    const int cb_di = (tid & 7) * 4;
    f32x4 cst = (f32x4){0.f, 0.f, 0.f, 0.f};
    __syncthreads();

    for (int t = 0; t < T_; ++t) {
      // Xg slice for this wave's outputs (cached; overlaps poll)
      float4 xg[2][2];
#pragma unroll
      for (int rt = 0; rt < 2; ++rt)
#pragma unroll
        for (int bt = 0; bt < 2; ++bt)
          xg[rt][bt] = *(const float4*)(Xg + ((long)t * B_ + bt * 16 + lr) * 2048 +
                                        g * 512 + w * 32 + rt * 16 + lkb * 4);

      f32x4 acc[2][2];
#pragma unroll
      for (int rt = 0; rt < 2; ++rt) {
        acc[rt][0] = (f32x4){0.f, 0.f, 0.f, 0.f};
        acc[rt][1] = (f32x4){0.f, 0.f, 0.f, 0.f};
      }

      if (t > 0) {
        // ---- poll tagged h: thread's 256B slice (32 units), expect tag t ----
        // (vmcnt(0) inside also drains this thread's step t-1 stores)
        const char* pb = hxc + (t & 1) * 65536 +
                         ((long)(tid >> 3) * 256 + (tid & 7) * 32) * 8;
        i32x4 u[16];
        for (int it = 0; it < SPIN_CAP; ++it) {
          PLOADS16(u, pb);
          bool ok = true;
#pragma unroll
          for (int i = 0; i < 16; ++i)
            ok = ok && (u[i][1] == t) && (u[i][3] == t);
          if (ok) break;
          __builtin_amdgcn_s_sleep(1);
        }
        // ---- strip tags -> stage (bf16 [b][512], xor-swizzled) ----
        int b_own = tid >> 3, j0b = (tid & 7) * 128;
#pragma unroll
        for (int c = 0; c < 8; ++c) {
          i32x4 pc = (i32x4){u[2*c][0], u[2*c][2], u[2*c+1][0], u[2*c+1][2]};
          *(i32x4*)(stage + b_own * 1024 + ((j0b + c * 16) ^ ((b_own & 7) << 4))) = pc;
        }
        __syncthreads();   // stage ready; all threads' prior stores drained

        // lazy consumer-epoch: stores through step t-1 are now visible
        if (tid == 0) DSTORE(flags + w * 32, (unsigned)t);

        // ---- MFMA: 2 row-tiles x 2 b-tiles x 16 kt ----
#pragma unroll
        for (int kt = 0; kt < 16; ++kt) {
          int b0r = lr, b1r = 16 + lr;
          i32x4 bv0 = *(const i32x4*)(stage + b0r * 1024 +
                                      ((kt * 64 + lkb * 16) ^ ((b0r & 7) << 4)));
          i32x4 bv1 = *(const i32x4*)(stage + b1r * 1024 +
                                      ((kt * 64 + lkb * 16) ^ ((b1r & 7) << 4)));
          bf16x8 b0 = *(bf16x8*)&bv0, b1 = *(bf16x8*)&bv1;
#pragma unroll
          for (int rt = 0; rt < 2; ++rt) {
            bf16x8 a;
            if (kt < 12) a = *(const bf16x8*)(wlds +
                             ((((wv * 2 + rt) * 12 + kt) * 64) + lane) * 16);
            else a = awr[rt][kt - 12];
            acc[rt][0] = __builtin_amdgcn_mfma_f32_16x16x32_bf16(a, b0, acc[rt][0], 0, 0, 0);
            acc[rt][1] = __builtin_amdgcn_mfma_f32_16x16x32_bf16(a, b1, acc[rt][1], 0, 0, 0);
          }
        }
      }

      // add Xg, write gate exchange (D: col=b, row=d-local)
#pragma unroll
      for (int rt = 0; rt < 2; ++rt)
#pragma unroll
        for (int bt = 0; bt < 2; ++bt) {
          int b = bt * 16 + lr;
          f32x4 r = acc[rt][bt];
          r[0] += xg[rt][bt].x; r[1] += xg[rt][bt].y;
          r[2] += xg[rt][bt].z; r[3] += xg[rt][bt].w;
          *(f32x4*)(gbufc + (g * 32 + b) * 128 +
                    (((rt * 16 + lkb * 4) * 4) ^ ((b & 7) << 4))) = r;
        }
      __syncthreads();

      // ---- cell update: 4 cells per thread ----
      int rb = (cb_di * 4) ^ ((cb_b & 7) << 4);
      float4 gi  = *(const float4*)(gbufc + (0 * 32 + cb_b) * 128 + rb);
      float4 gf  = *(const float4*)(gbufc + (1 * 32 + cb_b) * 128 + rb);
      float4 gg_ = *(const float4*)(gbufc + (2 * 32 + cb_b) * 128 + rb);
      float4 go  = *(const float4*)(gbufc + (3 * 32 + cb_b) * 128 + rb);
      float iv[4] = {gi.x, gi.y, gi.z, gi.w};
      float fv[4] = {gf.x, gf.y, gf.z, gf.w};
      float gv[4] = {gg_.x, gg_.y, gg_.z, gg_.w};
      float ov[4] = {go.x, go.y, go.z, go.w};
      unsigned short hb[4];
#pragma unroll
      for (int r = 0; r < 4; ++r) {
        float c_ = sigf(fv[r]) * cst[r] + sigf(iv[r]) * tanh_fast(gv[r]);
        cst[r] = c_;
        hb[r] = (unsigned short)f2bf(sigf(ov[r]) * tanh_fast(c_));
      }
      int pk0 = (int)((unsigned)hb[0] | ((unsigned)hb[1] << 16));
      int pk1 = (int)((unsigned)hb[2] | ((unsigned)hb[3] << 16));
      long ubase = (long)cb_b * 256 + w * 16 + (cb_di >> 1);  // 8B-unit index

      if (t < T_ - 1) {
        // tagged h exchange: parity (t+1)&1, tag t+1, fire-and-forget 16B
        i32x4 unit = (i32x4){pk0, t + 1, pk1, t + 1};
        QSTORE(hxc + ((t + 1) & 1) * 65536 + ubase * 8, unit);
      }
      if (t >= 1) {
        // plain hs for consumers (fire-and-forget; drained by next poll / final ack)
        i32x2 pk; pk[0] = pk0; pk[1] = pk1;
        DSTORE2(hs + ((long)(t - 1) * B_ + cb_b) * H_ + w * 32 + cb_di, pk);
      }
    }
    // terminal: drain final hs stores, publish final epoch
    asm volatile("s_waitcnt vmcnt(0)" ::: "memory");
    __syncthreads();
    if (tid == 0) DSTORE(flags + w * 32, (unsigned)(T_ + 1));

  } else if (blockIdx.x == NWG) {
    // ===================== aggregator role =====================
    if (tid < 64) {
      for (unsigned e = 2; e <= (unsigned)(T_ + 1); ++e) {
        for (int it = 0; it < SPIN_CAP; ++it) {
          unsigned f = (lane < NWG) ? prog_load(flags + lane * 32) : 0xFFFFFFFFu;
          if (__ballot(f >= e) == ~0ULL) break;
          __builtin_amdgcn_s_sleep(2);
        }
        DSTORE(replicas + lane * 32, e);
      }
    }
  } else {
    // ===================== head-consumer role =====================
    char* stage = lds;                        // 16KB hs m-tile, swizzled
    const int cid = blockIdx.x - NWG - 1;     // 0..124, owns v [cid*256, +256)

    bf16x8 bw[4][16];
    float bias[4];
#pragma unroll
    for (int j = 0; j < 4; ++j) {
      int v = cid * 256 + j * 64 + wv * 16 + lr;
#pragma unroll
      for (int kt = 0; kt < 16; ++kt)
        bw[j][kt] = load_cvt8(W_head + (long)v * E_ + kt * 32 + lkb * 8);
      bias[j] = b_head[v];
    }

    for (int mt = 0; mt < 94; ++mt) {
      // rows of step mt/2+1; hs of step s visible when epoch >= s+1 -> use +2
      int tagneed = mt / 2 + 2;
      if (tid == 0) {
        const unsigned* rp = replicas + (cid & 63) * 32;
        for (int it = 0; it < SPIN_CAP; ++it) {
          if (prog_load(rp) >= (unsigned)tagneed) break;
          __builtin_amdgcn_s_sleep(32);
        }
      }
      __syncthreads();   // release block; also guards stage reuse

      const char* src = (const char*)(hs + (long)mt * 16 * H_) + tid * 64;
      i32x4 st[4];
      CLOADS4(st, src);
#pragma unroll
      for (int i = 0; i < 4; ++i) {
        int c = tid * 4 + i;
        int row = c >> 6;
        int cb  = (c & 63) * 16;
        *(i32x4*)(stage + row * 1024 + (cb ^ ((row & 7) << 4))) = st[i];
      }
      __syncthreads();

      f32x4 acc[4];
#pragma unroll
      for (int j = 0; j < 4; ++j)
        acc[j] = (f32x4){bias[j], bias[j], bias[j], bias[j]};
#pragma unroll
      for (int kt = 0; kt < 16; ++kt) {
        int cb = kt * 64 + lkb * 16;
        i32x4 av = *(const i32x4*)(stage + lr * 1024 + (cb ^ ((lr & 7) << 4)));
        bf16x8 a = *(bf16x8*)&av;
#pragma unroll
        for (int j = 0; j < 4; ++j)
          acc[j] = __builtin_amdgcn_mfma_f32_16x16x32_bf16(a, bw[j][kt], acc[j], 0, 0, 0);
      }

#pragma unroll
      for (int j = 0; j < 4; ++j)
#pragma unroll
        for (int r = 0; r < 4; ++r) {
          int R = mt * 16 + lkb * 4 + r;        // hs row; out row = R + 32
          out[(long)(R + 32) * V_ + cid * 256 + j * 64 + wv * 16 + lr] = acc[j][r];
        }
    }
  }
}

// ---------------------------------------------------------------------------
extern "C" void kernel_launch(void* const* d_in, const int* in_sizes, int n_in,
                              void* d_out, int out_size, void* d_ws, size_t ws_size,
                              hipStream_t stream) {
  const float* img  = (const float*)d_in[0];
  const int*   gt   = (const int*)d_in[1];
  const float* emb  = (const float*)d_in[2];
  const float* W_ih = (const float*)d_in[3];
  const float* W_hh = (const float*)d_in[4];
  const float* b_ih = (const float*)d_in[5];
  const float* b_hh = (const float*)d_in[6];
  const float* W_hd = (const float*)d_in[7];
  const float* b_hd = (const float*)d_in[8];
  float* out = (float*)d_out;

  char* ws = (char*)d_ws;
  unsigned*       flags = (unsigned*)(ws);                   // 16 lines
  unsigned*       repl  = (unsigned*)(ws + 8192);            // 64 lines
  char*           hxc   = ws + 16384;                        // 131072 B tagged
  unsigned short* hs    = (unsigned short*)(ws + 147456);    // 1540096 B
  float*          Xg    = (float*)(ws + 1687552);            // 12582912 B

  hipMemsetAsync(ws, 0, 147456, stream);     // flags + replicas + hxc tags
  hipMemsetAsync(out, 0, (size_t)B_ * V_ * sizeof(float), stream);  // outputs[0]=0

  dim3 g1(48, 8);
  k_xg<<<g1, 256, 0, stream>>>(img, gt, emb, W_ih, b_ih, b_hh, Xg);
  k_fused<<<GRID, 256, 0, stream>>>(W_hh, Xg, W_hd, b_hd, flags, repl, hxc, hs, out);
}

// Round 16
// 272.263 us; speedup vs baseline: 1.3222x; 1.3222x over previous
//
#include <hip/hip_runtime.h>
#include <hip/hip_bf16.h>

#define V_ 32000
#define E_ 512
#define H_ 512
#define B_ 32
#define T_ 48
#define NWG 64          // recurrence workgroups (blocks 0..63)
#define NCON 250        // head-consumer workgroups (blocks 65..314)
#define GRID (NWG + 1 + NCON)
#define SPIN_CAP (1 << 20)

typedef __attribute__((ext_vector_type(8))) short bf16x8;
typedef __attribute__((ext_vector_type(4))) float f32x4;
typedef __attribute__((ext_vector_type(4))) int   i32x4;

static __device__ __forceinline__ short f2bf(float f) {
  union { __hip_bfloat16 h; short s; } u;
  u.h = __float2bfloat16(f);
  return u.s;
}

static __device__ __forceinline__ bf16x8 load_cvt8(const float* p) {
  float4 a = *(const float4*)p;
  float4 b = *(const float4*)(p + 4);
  bf16x8 r;
  r[0] = f2bf(a.x); r[1] = f2bf(a.y); r[2] = f2bf(a.z); r[3] = f2bf(a.w);
  r[4] = f2bf(b.x); r[5] = f2bf(b.y); r[6] = f2bf(b.z); r[7] = f2bf(b.w);
  return r;
}

static __device__ __forceinline__ float sigf(float x) {
  return 1.0f / (1.0f + __expf(-x));
}
static __device__ __forceinline__ float tanh_fast(float x) {
  float e = __expf(2.0f * x);
  return (e - 1.0f) / (e + 1.0f);
}

// device-coherent 4B load, acked
static __device__ __forceinline__ unsigned prog_load(const unsigned* p) {
  unsigned v;
  asm volatile("global_load_dword %0, %1, off sc0 sc1\n\t"
               "s_waitcnt vmcnt(0)"
               : "=&v"(v) : "v"(p) : "memory");
  return v;
}

// coherent stores, fire-and-forget
#define DSTORE(ADDR, VAL)                                              \
  asm volatile("global_store_dword %0, %1, off sc0 sc1"                \
               :: "v"(ADDR), "v"(VAL) : "memory")

// ---------------------------------------------------------------------------
// Kernel 1: Xg[t][b][j] = x_t[b] @ W_ih^T [j] + b_ih[j] + b_hh[j]
// ---------------------------------------------------------------------------
__global__ __launch_bounds__(256) void k_xg(
    const float* __restrict__ img,   // [32][512]
    const int*   __restrict__ gt,    // [32][48]
    const float* __restrict__ emb,   // [32000][512]
    const float* __restrict__ W_ih,  // [2048][512]
    const float* __restrict__ b_ih,
    const float* __restrict__ b_hh,
    float* __restrict__ Xg)          // [48][32][2048]
{
  const int s    = blockIdx.x;
  const int lane = threadIdx.x & 63;
  const int wv   = threadIdx.x >> 6;
  const int nbase = blockIdx.y * 256 + wv * 64;
  const int lr  = lane & 15;
  const int lkb = lane >> 4;

  const float* arow[2];
#pragma unroll
  for (int m = 0; m < 2; ++m) {
    int b = m * 16 + lr;
    const float* src;
    if (s == 0) {
      src = img + b * E_;
    } else {
      int tok = (s == 1) ? 1 : gt[b * T_ + (s - 1)];
      src = emb + (long)tok * E_;
    }
    arow[m] = src;
  }

  f32x4 acc[2][4];
#pragma unroll
  for (int m = 0; m < 2; ++m)
#pragma unroll
    for (int n = 0; n < 4; ++n) acc[m][n] = (f32x4){0.f, 0.f, 0.f, 0.f};

  for (int kt = 0; kt < 16; ++kt) {
    int ko = kt * 32 + lkb * 8;
    bf16x8 a0 = load_cvt8(arow[0] + ko);
    bf16x8 a1 = load_cvt8(arow[1] + ko);
#pragma unroll
    for (int n = 0; n < 4; ++n) {
      const float* wp = W_ih + (long)(nbase + n * 16 + lr) * E_ + ko;
      bf16x8 bw = load_cvt8(wp);
      acc[0][n] = __builtin_amdgcn_mfma_f32_16x16x32_bf16(a0, bw, acc[0][n], 0, 0, 0);
      acc[1][n] = __builtin_amdgcn_mfma_f32_16x16x32_bf16(a1, bw, acc[1][n], 0, 0, 0);
    }
  }

#pragma unroll
  for (int n = 0; n < 4; ++n) {
    int j = nbase + n * 16 + lr;
    float bias = b_ih[j] + b_hh[j];
#pragma unroll
    for (int m = 0; m < 2; ++m) {
#pragma unroll
      for (int r = 0; r < 4; ++r) {
        int b = m * 16 + lkb * 4 + r;
        Xg[((long)(s * B_ + b) * 2048) + j] = acc[m][n][r] + bias;
      }
    }
  }
}

// ---------------------------------------------------------------------------
// Kernel 2 (fused): R13 structure + rotating h buffers + PLAIN cached reads.
//  Writes: h/hs stores stay sc0/sc1 write-through; ack -> flag (R13 chain).
//  Reads: hrot[t] / hs addresses are written once and read once per run, so
//  after the entry acquire-fence (invalidates stale L1/L2 from prior replay)
//  a plain cached load can never see stale data -> XCD L2 amortizes the
//  16-64 readers instead of the coherence point serializing them.
//  blocks 0..63   : recurrence. WG w owns hidden dims [8w, 8w+8).
//  block 64       : aggregator: 64 flags -> 64 epoch replica lines.
//  blocks 65..314 : head consumers; poll ONE replica line, plain bulk hs read.
// All spins bounded. 315 blocks x 68KB -> 2/CU -> co-resident.
// ---------------------------------------------------------------------------
__global__ __launch_bounds__(256, 2) void k_fused(
    const float* __restrict__ W_hh,      // [2048][512]
    const float* __restrict__ Xg,        // [48][32][2048]
    const float* __restrict__ W_head,    // [32000][512]
    const float* __restrict__ b_head,    // [32000]
    unsigned* __restrict__ flags,        // [64] lines (128B apart)
    unsigned* __restrict__ replicas,     // [64] lines (128B apart)
    unsigned short* __restrict__ hrot,   // [48][32][512] bf16 rotating
    unsigned short* __restrict__ hs,     // [1504][512] bf16 plain
    float* __restrict__ out)             // [48][32][32000]
{
  __shared__ __align__(16) char lds[69632];  // 32K wlds + 32K stage + 4K gbuf
  const int tid  = threadIdx.x;
  const int lane = tid & 63;
  const int wv   = tid >> 6;
  const int lr   = lane & 15;
  const int lkb  = lane >> 4;

  // kill stale L1/L2 lines from the previous graph replay (once per block)
  __builtin_amdgcn_fence(__ATOMIC_ACQUIRE, "agent");

  if (blockIdx.x < NWG) {
    // ===================== recurrence role =====================
    char* wlds  = lds;            // [2 pair][16 kt][64 lane][16B] = 32KB
    char* stage = lds + 32768;    // pure h [32 b][512 dim] bf16, swizzled
    char* gbufc = lds + 65536;    // [4 gate][32 b][8 dim] f32 = 4KB
    const int w = blockIdx.x;     // owns hidden dims [8w, 8w+8)
    const int p  = wv & 1;        // gate pair: gates 2p, 2p+1
    const int nt = wv >> 1;       // b-tile

    // preload W_hh fragments (waves 0,1 load pair wv)
    if (wv < 2) {
#pragma unroll
      for (int kt = 0; kt < 16; ++kt) {
        int g = 2 * wv + (lr >> 3);
        int row = g * 512 + w * 8 + (lr & 7);
        bf16x8 wf = load_cvt8(W_hh + (long)row * E_ + kt * 32 + lkb * 8);
        *(bf16x8*)(wlds + (((wv * 16 + kt) * 64) + lane) * 16) = wf;
      }
    }
    __syncthreads();

    // cell state: threads 0..127, b = tid>>2, local dims d0, d0+1
    const int cb_b  = tid >> 2;
    const int cb_d0 = (tid & 3) * 2;
    float c0 = 0.f, c1 = 0.f;

    for (int t = 0; t < T_; ++t) {
      const int bb = nt * 16 + lr;

      // Xg slice (cached loads; overlaps the flag wait)
      float4 xg = *(const float4*)(Xg + ((long)t * B_ + bb) * 2048 +
                                   (2 * p + (lkb >> 1)) * 512 + w * 8 + (lkb & 1) * 4);

      f32x4 acc = (f32x4){0.f, 0.f, 0.f, 0.f};

      if (t > 0) {
        // ---- flag ballot: wave 0, one flag line per lane, until all >= t ----
        if (wv == 0) {
          const unsigned* fp = flags + lane * 32;
          for (int it = 0; it < SPIN_CAP; ++it) {
            unsigned v = prog_load(fp);
            if (__ballot(v >= (unsigned)t) == ~0ULL) break;
            __builtin_amdgcn_s_sleep(1);
          }
        }
        __syncthreads();   // all waves released; h(t-1) visible at L3

        // ---- PLAIN cached bulk h read: thread's 128B of hrot[t-1] ----
        // (address never cached before in this run -> cannot be stale;
        //  first toucher per XCD fills L2, co-XCD blocks hit)
        const i32x4* src = (const i32x4*)((const char*)hrot +
                                          (long)(t - 1) * 32768 + tid * 128);
        i32x4 u[8];
#pragma unroll
        for (int c = 0; c < 8; ++c) u[c] = src[c];

        // ---- copy -> stage (bf16 [b][512], xor-swizzled) ----
        int b_own = tid >> 3, j0b = (tid & 7) * 128;
#pragma unroll
        for (int c = 0; c < 8; ++c)
          *(i32x4*)(stage + b_own * 1024 + ((j0b + c * 16) ^ ((b_own & 7) << 4))) = u[c];
        __syncthreads();   // stage ready; also fences gbuf(t-1) cell reads

        // ---- MFMA: A = W rows (2 gates x 8 dims), B = h ----
#pragma unroll
        for (int kt = 0; kt < 16; ++kt) {
          bf16x8 a = *(const bf16x8*)(wlds + (((p * 16 + kt) * 64) + lane) * 16);
          i32x4 bv = *(const i32x4*)(stage + bb * 1024 +
                                     ((kt * 64 + lkb * 16) ^ ((bb & 7) << 4)));
          acc = __builtin_amdgcn_mfma_f32_16x16x32_bf16(a, *(bf16x8*)&bv, acc, 0, 0, 0);
        }
      }

      // add Xg, write gate exchange
      acc[0] += xg.x; acc[1] += xg.y; acc[2] += xg.z; acc[3] += xg.w;
      int gp = 2 * p + (lkb >> 1);
      *(f32x4*)(gbufc + (gp * 32 + bb) * 32 + (((lkb & 1) * 16) ^ ((bb & 1) << 4))) = acc;
      __syncthreads();

      // ---- cell update + stores (threads 0..127) ----
      if (tid < 128) {
        int b = cb_b, d0 = cb_d0;
        int blk = ((d0 >= 4) ? 16 : 0) ^ ((b & 1) << 4);
        int inn = (d0 & 3) * 4;
        float2 gi  = *(const float2*)(gbufc + (0 * 32 + b) * 32 + blk + inn);
        float2 gf  = *(const float2*)(gbufc + (1 * 32 + b) * 32 + blk + inn);
        float2 gg_ = *(const float2*)(gbufc + (2 * 32 + b) * 32 + blk + inn);
        float2 go  = *(const float2*)(gbufc + (3 * 32 + b) * 32 + blk + inn);

        float cn0 = sigf(gf.x) * c0 + sigf(gi.x) * tanh_fast(gg_.x);
        float cn1 = sigf(gf.y) * c1 + sigf(gi.y) * tanh_fast(gg_.y);
        c0 = cn0; c1 = cn1;
        unsigned short h0 = (unsigned short)f2bf(sigf(go.x) * tanh_fast(cn0));
        unsigned short h1 = (unsigned short)f2bf(sigf(go.y) * tanh_fast(cn1));
        unsigned pk = (unsigned)h0 | ((unsigned)h1 << 16);

        if (t < T_ - 1) {
          // write-through h store into rotating slot t (read at step t+1)
          unsigned short* hn = hrot + (long)t * (B_ * H_) + b * H_ + w * 8 + d0;
          DSTORE(hn, pk);
        }
        if (t >= 1) {
          // write-through hs store for consumers
          unsigned short* hp = hs + ((long)(t - 1) * B_ + b) * H_ + w * 8 + d0;
          DSTORE(hp, pk);
        }
      }
      // ack all stores, then publish per-WG flag
      asm volatile("s_waitcnt vmcnt(0)" ::: "memory");
      __syncthreads();
      if (tid == 0) {
        unsigned val = (unsigned)(t + 1);
        DSTORE(flags + w * 32, val);
      }
    }
  } else if (blockIdx.x == NWG) {
    // ===================== aggregator role =====================
    if (tid < 64) {
      for (unsigned e = 2; e <= (unsigned)T_; ++e) {
        for (int it = 0; it < SPIN_CAP; ++it) {
          unsigned f = prog_load(flags + lane * 32);   // lane <-> producer WG
          if (__ballot(f >= e) == ~0ULL) break;
          __builtin_amdgcn_s_sleep(2);
        }
        DSTORE(replicas + lane * 32, e);
      }
    }
  } else {
    // ===================== head-consumer role =====================
    char* stage = lds;                        // 16KB hs m-tile, swizzled
    const int cid = blockIdx.x - NWG - 1;     // 0..249, owns v [cid*128, +128)
    const int vA = cid * 128 + wv * 16 + lr;
    const int vB = vA + 64;

    bf16x8 bwA[16], bwB[16];
#pragma unroll
    for (int kt = 0; kt < 16; ++kt) {
      bwA[kt] = load_cvt8(W_head + (long)vA * E_ + kt * 32 + lkb * 8);
      bwB[kt] = load_cvt8(W_head + (long)vB * E_ + kt * 32 + lkb * 8);
    }
    float biasA = b_head[vA];
    float biasB = b_head[vB];

    for (int mt = 0; mt < 94; ++mt) {
      int tagneed = (mt * 16) / 32 + 2;   // epoch that publishes this tile
      if (tid == 0) {
        const unsigned* rp = replicas + (cid & 63) * 32;
        for (int it = 0; it < SPIN_CAP; ++it) {
          if (prog_load(rp) >= (unsigned)tagneed) break;
          __builtin_amdgcn_s_sleep(32);
        }
      }
      __syncthreads();   // release block; also guards stage reuse

      // PLAIN cached bulk hs read (flag-gated; addresses fresh this run)
      const i32x4* src = (const i32x4*)((const char*)(hs + (long)mt * 16 * H_) + tid * 64);
      i32x4 st[4];
#pragma unroll
      for (int i = 0; i < 4; ++i) st[i] = src[i];
#pragma unroll
      for (int i = 0; i < 4; ++i) {
        int c = tid * 4 + i;
        int row = c >> 6;
        int cb  = (c & 63) * 16;
        *(i32x4*)(stage + row * 1024 + (cb ^ ((row & 7) << 4))) = st[i];
      }
      __syncthreads();

      f32x4 accA = (f32x4){biasA, biasA, biasA, biasA};
      f32x4 accB = (f32x4){biasB, biasB, biasB, biasB};
#pragma unroll
      for (int kt = 0; kt < 16; ++kt) {
        int cb = kt * 64 + lkb * 16;
        i32x4 av = *(const i32x4*)(stage + lr * 1024 + (cb ^ ((lr & 7) << 4)));
        bf16x8 a = *(bf16x8*)&av;
        accA = __builtin_amdgcn_mfma_f32_16x16x32_bf16(a, bwA[kt], accA, 0, 0, 0);
        accB = __builtin_amdgcn_mfma_f32_16x16x32_bf16(a, bwB[kt], accB, 0, 0, 0);
      }

#pragma unroll
      for (int r = 0; r < 4; ++r) {
        int R = mt * 16 + lkb * 4 + r;          // hs row; out row = R + 32
        out[(long)(R + 32) * V_ + vA] = accA[r];
        out[(long)(R + 32) * V_ + vB] = accB[r];
      }
    }
  }
}

// ---------------------------------------------------------------------------
extern "C" void kernel_launch(void* const* d_in, const int* in_sizes, int n_in,
                              void* d_out, int out_size, void* d_ws, size_t ws_size,
                              hipStream_t stream) {
  const float* img  = (const float*)d_in[0];
  const int*   gt   = (const int*)d_in[1];
  const float* emb  = (const float*)d_in[2];
  const float* W_ih = (const float*)d_in[3];
  const float* W_hh = (const float*)d_in[4];
  const float* b_ih = (const float*)d_in[5];
  const float* b_hh = (const float*)d_in[6];
  const float* W_hd = (const float*)d_in[7];
  const float* b_hd = (const float*)d_in[8];
  float* out = (float*)d_out;

  char* ws = (char*)d_ws;
  unsigned*       flags = (unsigned*)(ws);                   // 64 lines (8192 B)
  unsigned*       repl  = (unsigned*)(ws + 8192);            // 64 lines (8192 B)
  unsigned short* hrot  = (unsigned short*)(ws + 16384);     // 48*32768 = 1572864 B
  unsigned short* hs    = (unsigned short*)(ws + 16384 + 1572864);   // 1540096 B
  float*          Xg    = (float*)(ws + 16384 + 1572864 + 1540096);  // 12582912 B

  hipMemsetAsync(ws, 0, 16384, stream);                      // flags + replicas
  hipMemsetAsync(out, 0, (size_t)B_ * V_ * sizeof(float), stream);  // outputs[0]=0

  dim3 g1(48, 8);
  k_xg<<<g1, 256, 0, stream>>>(img, gt, emb, W_ih, b_ih, b_hh, Xg);
  k_fused<<<GRID, 256, 0, stream>>>(W_hh, Xg, W_hd, b_hd, flags, repl, hrot, hs, out);
}